// Round 1
// baseline (2050.045 us; speedup 1.0000x reference)
//
#include <hip/hip_runtime.h>
#include <math.h>

constexpr int Tq = 2048;
constexpr int D  = 1024;
constexpr int NHc = 16;
constexpr int Bc = 2;
constexpr int Mrows = Bc * Tq;   // 4096

__device__ __forceinline__ float wsum(float v){
#pragma unroll
  for(int o=32;o;o>>=1) v += __shfl_xor(v,o);
  return v;
}
__device__ __forceinline__ float wmax(float v){
#pragma unroll
  for(int o=32;o;o>>=1) v = fmaxf(v,__shfl_xor(v,o));
  return v;
}

// ---------------- LayerNorm: one block per row (D=1024, 256 thr x float4) ---
__global__ __launch_bounds__(256) void ln_kernel(const float* __restrict__ x,
    const float* __restrict__ g, const float* __restrict__ b,
    float* __restrict__ xn){
  const int row = blockIdx.x;
  const int tid = threadIdx.x;
  const float4 v = ((const float4*)(x + (size_t)row*D))[tid];
  float s = v.x+v.y+v.z+v.w;
  float q = v.x*v.x+v.y*v.y+v.z*v.z+v.w*v.w;
  s = wsum(s); q = wsum(q);
  __shared__ float sb[4], qb[4];
  if((tid&63)==0){ sb[tid>>6]=s; qb[tid>>6]=q; }
  __syncthreads();
  const float ts = sb[0]+sb[1]+sb[2]+sb[3];
  const float tq = qb[0]+qb[1]+qb[2]+qb[3];
  const float mu   = ts*(1.0f/D);
  const float var  = tq*(1.0f/D) - mu*mu;
  const float rstd = rsqrtf(var + 1e-5f);
  const float4 gv = ((const float4*)g)[tid];
  const float4 bv = ((const float4*)b)[tid];
  float4 o;
  o.x = (v.x-mu)*rstd*gv.x + bv.x;
  o.y = (v.y-mu)*rstd*gv.y + bv.y;
  o.z = (v.z-mu)*rstd*gv.z + bv.z;
  o.w = (v.w-mu)*rstd*gv.w + bv.w;
  ((float4*)(xn + (size_t)row*D))[tid] = o;
}

// ---------------- NT GEMM: C[m,n] = sum_k A[m,k]*B[n,k] (+bias[n]) (+resid) -
// 64x64 tile, BK=16, 256 threads, 4x4 micro-tile.
__global__ __launch_bounds__(256) void gemm_nt(const float* __restrict__ A,
    const float* __restrict__ Bm, float* __restrict__ C,
    const float* __restrict__ bias, const float* __restrict__ resid,
    int K, int lda, int ldb, int ldc){
  __shared__ float As[16][64];
  __shared__ float Bs[16][64];
  const int tid = threadIdx.x;
  const int tx = tid & 15, ty = tid >> 4;
  const int mBase = blockIdx.y*64, nBase = blockIdx.x*64;
  const int lr = tid >> 2, lc = tid & 3;
  const float* Ap = A  + (size_t)(mBase+lr)*lda + lc*4;
  const float* Bp = Bm + (size_t)(nBase+lr)*ldb + lc*4;
  float acc[4][4] = {};
  for(int k0=0;k0<K;k0+=16){
    const float4 a4 = *(const float4*)(Ap + k0);
    const float4 b4 = *(const float4*)(Bp + k0);
    As[lc*4+0][lr]=a4.x; As[lc*4+1][lr]=a4.y; As[lc*4+2][lr]=a4.z; As[lc*4+3][lr]=a4.w;
    Bs[lc*4+0][lr]=b4.x; Bs[lc*4+1][lr]=b4.y; Bs[lc*4+2][lr]=b4.z; Bs[lc*4+3][lr]=b4.w;
    __syncthreads();
#pragma unroll
    for(int kk=0;kk<16;kk++){
      const float4 av = *(const float4*)&As[kk][ty*4];
      const float4 bv = *(const float4*)&Bs[kk][tx*4];
      const float a[4]={av.x,av.y,av.z,av.w};
      const float b2[4]={bv.x,bv.y,bv.z,bv.w};
#pragma unroll
      for(int i=0;i<4;i++)
#pragma unroll
        for(int j=0;j<4;j++)
          acc[i][j] = fmaf(a[i], b2[j], acc[i][j]);
    }
    __syncthreads();
  }
#pragma unroll
  for(int i=0;i<4;i++){
    const int m = mBase + ty*4 + i;
    const int n = nBase + tx*4;
    float4 o = make_float4(acc[i][0],acc[i][1],acc[i][2],acc[i][3]);
    if(bias){
      const float4 bb = *(const float4*)(bias + n);
      o.x+=bb.x; o.y+=bb.y; o.z+=bb.z; o.w+=bb.w;
    }
    if(resid){
      const float4 r4 = *(const float4*)(resid + (size_t)m*ldc + n);
      o.x+=r4.x; o.y+=r4.y; o.z+=r4.z; o.w+=r4.w;
    }
    *(float4*)(C + (size_t)m*ldc + n) = o;
  }
}

// ---------------- RoPE (split-half), in place on q1 and k1 ------------------
__global__ __launch_bounds__(256) void rope_kernel(float* __restrict__ q,
                                                   float* __restrict__ k){
  const int idx = blockIdx.x*256 + threadIdx.x;   // 0 .. Mrows*512-1
  const int m = idx >> 9;          // row in (B*T, D)
  const int r = idx & 511;
  const int h = r >> 5, i = r & 31;
  const int t = m & (Tq-1);        // position within sequence
  const float inv_freq = powf(10000.0f, -(float)i*(1.0f/32.0f)); // 2i/64
  const float ang = (float)t * inv_freq;
  const float c = cosf(ang), s = sinf(ang);
  const size_t base = (size_t)m*D + h*64 + i;
  const float a0=q[base], a1=q[base+32];
  q[base]    = a0*c - a1*s;
  q[base+32] = a1*c + a0*s;
  const float b0=k[base], b1=k[base+32];
  k[base]    = b0*c - b1*s;
  k[base+32] = b1*c + b0*s;
}

// ---------------- scores: S = 0.125 * Qh @ Khᵀ, lower-tri tiles only --------
__global__ __launch_bounds__(256) void scores_kernel(const float* __restrict__ q2,
    const float* __restrict__ k2, float* __restrict__ attnW){
  const int tCol = blockIdx.x, tRow = blockIdx.y;
  if(tCol > tRow) return;                  // fully masked tile, never read
  const int bh = blockIdx.z; const int b = bh >> 4, h = bh & 15;
  const float* A  = q2 + (size_t)b*Tq*D + h*64;
  const float* B0 = k2 + (size_t)b*Tq*D + h*64;
  float* Cp = attnW + (size_t)bh*Tq*Tq;
  __shared__ float As[16][64];
  __shared__ float Bs[16][64];
  const int tid = threadIdx.x;
  const int tx = tid & 15, ty = tid >> 4;
  const int mBase = tRow*64, nBase = tCol*64;
  const int lr = tid >> 2, lc = tid & 3;
  const float* Ap = A  + (size_t)(mBase+lr)*D + lc*4;
  const float* Bp = B0 + (size_t)(nBase+lr)*D + lc*4;
  float acc[4][4] = {};
  for(int k0=0;k0<64;k0+=16){
    const float4 a4 = *(const float4*)(Ap + k0);
    const float4 b4 = *(const float4*)(Bp + k0);
    As[lc*4+0][lr]=a4.x; As[lc*4+1][lr]=a4.y; As[lc*4+2][lr]=a4.z; As[lc*4+3][lr]=a4.w;
    Bs[lc*4+0][lr]=b4.x; Bs[lc*4+1][lr]=b4.y; Bs[lc*4+2][lr]=b4.z; Bs[lc*4+3][lr]=b4.w;
    __syncthreads();
#pragma unroll
    for(int kk=0;kk<16;kk++){
      const float4 av = *(const float4*)&As[kk][ty*4];
      const float4 bv = *(const float4*)&Bs[kk][tx*4];
      const float a[4]={av.x,av.y,av.z,av.w};
      const float b2[4]={bv.x,bv.y,bv.z,bv.w};
#pragma unroll
      for(int i=0;i<4;i++)
#pragma unroll
        for(int j=0;j<4;j++)
          acc[i][j] = fmaf(a[i], b2[j], acc[i][j]);
    }
    __syncthreads();
  }
#pragma unroll
  for(int i=0;i<4;i++){
    const int t = mBase + ty*4 + i;
    const int s0 = nBase + tx*4;
    float4 o;
    o.x = (s0+0<=t)? acc[i][0]*0.125f : -1e30f;
    o.y = (s0+1<=t)? acc[i][1]*0.125f : -1e30f;
    o.z = (s0+2<=t)? acc[i][2]*0.125f : -1e30f;
    o.w = (s0+3<=t)? acc[i][3]*0.125f : -1e30f;
    *(float4*)(Cp + (size_t)t*Tq + s0) = o;
  }
}

// ---------------- row softmax in place (writes zeros where s > t) -----------
__global__ __launch_bounds__(256) void softmax_kernel(float* __restrict__ attnW){
  const int t  = blockIdx.x;
  const int bh = blockIdx.y;
  float* row = attnW + (size_t)bh*Tq*Tq + (size_t)t*Tq;
  const int tid = threadIdx.x;
  const float4 v0 = ((const float4*)row)[tid*2];
  const float4 v1 = ((const float4*)row)[tid*2+1];
  float vals[8] = {v0.x,v0.y,v0.z,v0.w,v1.x,v1.y,v1.z,v1.w};
  const int s0 = tid*8;
  float mx = -1e30f;
#pragma unroll
  for(int p=0;p<8;p++){
    if(s0+p > t) vals[p] = -1e30f;     // masked (memory there may be garbage)
    mx = fmaxf(mx, vals[p]);
  }
  mx = wmax(mx);
  __shared__ float sm[4], ss[4];
  if((tid&63)==0) sm[tid>>6]=mx;
  __syncthreads();
  mx = fmaxf(fmaxf(sm[0],sm[1]), fmaxf(sm[2],sm[3]));
  float lsum = 0.f;
#pragma unroll
  for(int p=0;p<8;p++){ vals[p] = __expf(vals[p]-mx); lsum += vals[p]; }
  lsum = wsum(lsum);
  if((tid&63)==0) ss[tid>>6]=lsum;
  __syncthreads();
  const float inv = 1.0f/(ss[0]+ss[1]+ss[2]+ss[3]);
  ((float4*)row)[tid*2]   = make_float4(vals[0]*inv, vals[1]*inv, vals[2]*inv, vals[3]*inv);
  ((float4*)row)[tid*2+1] = make_float4(vals[4]*inv, vals[5]*inv, vals[6]*inv, vals[7]*inv);
}

// ---------------- PV: O = P @ Vh (skip upper-tri s-tiles) -------------------
__global__ __launch_bounds__(256) void pv_kernel(const float* __restrict__ attnW,
    const float* __restrict__ v2, float* __restrict__ o){
  const int tRow = blockIdx.y;
  const int bh = blockIdx.z; const int b = bh >> 4, h = bh & 15;
  const float* A  = attnW + (size_t)bh*Tq*Tq;         // (T,T), lda=T
  const float* Bv = v2 + (size_t)b*Tq*D + h*64;       // (T,64), stride D
  float* Co = o + (size_t)b*Tq*D + h*64;              // (T,64), stride D
  __shared__ float As[16][64];
  __shared__ float Bs[16][64];
  const int tid = threadIdx.x;
  const int tx = tid & 15, ty = tid >> 4;
  const int mBase = tRow*64;
  const int lr = tid >> 2, lc = tid & 3;
  const int br = tid >> 4, bc = tid & 15;
  float acc[4][4] = {};
  const int kMax = (tRow+1)*64;                       // causal: P==0 beyond
  for(int k0=0;k0<kMax;k0+=16){
    const float4 a4 = *(const float4*)(A + (size_t)(mBase+lr)*Tq + k0 + lc*4);
    const float4 b4 = *(const float4*)(Bv + (size_t)(k0+br)*D + bc*4);
    As[lc*4+0][lr]=a4.x; As[lc*4+1][lr]=a4.y; As[lc*4+2][lr]=a4.z; As[lc*4+3][lr]=a4.w;
    *(float4*)&Bs[br][bc*4] = b4;
    __syncthreads();
#pragma unroll
    for(int kk=0;kk<16;kk++){
      const float4 av = *(const float4*)&As[kk][ty*4];
      const float4 bv = *(const float4*)&Bs[kk][tx*4];
      const float a[4]={av.x,av.y,av.z,av.w};
      const float b2[4]={bv.x,bv.y,bv.z,bv.w};
#pragma unroll
      for(int i=0;i<4;i++)
#pragma unroll
        for(int j=0;j<4;j++)
          acc[i][j] = fmaf(a[i], b2[j], acc[i][j]);
    }
    __syncthreads();
  }
#pragma unroll
  for(int i=0;i<4;i++){
    *(float4*)(Co + (size_t)(mBase+ty*4+i)*D + tx*4)
        = make_float4(acc[i][0],acc[i][1],acc[i][2],acc[i][3]);
  }
}

extern "C" void kernel_launch(void* const* d_in, const int* in_sizes, int n_in,
                              void* d_out, int out_size, void* d_ws, size_t ws_size,
                              hipStream_t stream){
  const float* x    = (const float*)d_in[0];
  const float* Win  = (const float*)d_in[1];   // (3072,1024) rows: q,k,v
  const float* bin  = (const float*)d_in[2];   // (3072)
  const float* Wout = (const float*)d_in[3];   // (1024,1024)
  const float* bout = (const float*)d_in[4];   // (1024)
  const float* gam  = (const float*)d_in[5];
  const float* bet  = (const float*)d_in[6];

  float* out   = (float*)d_out;                       // (B,T,D) = 4,194,304
  float* attnW = out + (size_t)Mrows*D;               // (B,H,T,T)

  // 4 recycled 16MB slots: ws0 xn->q2, ws1 q1->k2, ws2 k1->v2, ws3 v1->attn_out
  const size_t SLOT = (size_t)Mrows*D;
  float* ws0 = (float*)d_ws;
  float* ws1 = ws0 + SLOT;
  float* ws2 = ws0 + 2*SLOT;
  float* ws3 = ws0 + 3*SLOT;

  // 1) LayerNorm
  ln_kernel<<<Mrows, 256, 0, stream>>>(x, gam, bet, ws0);

  // 2) first projection: q1,k1,v1 = xn @ W{q,k,v}ᵀ + b
  const dim3 gp(D/64, Mrows/64);   // (16,64)
  gemm_nt<<<gp,256,0,stream>>>(ws0, Win,                ws1, bin,      nullptr, D, D, D, D);
  gemm_nt<<<gp,256,0,stream>>>(ws0, Win + (size_t)D*D,  ws2, bin+D,    nullptr, D, D, D, D);
  gemm_nt<<<gp,256,0,stream>>>(ws0, Win + (size_t)2*D*D,ws3, bin+2*D,  nullptr, D, D, D, D);

  // 3) RoPE on q1,k1 in place
  rope_kernel<<<(Mrows*512)/256, 256, 0, stream>>>(ws1, ws2);

  // 4) second projection (no bias): q2=ws0, k2=ws1, v2=ws2
  gemm_nt<<<gp,256,0,stream>>>(ws1, Win,                ws0, nullptr, nullptr, D, D, D, D);
  gemm_nt<<<gp,256,0,stream>>>(ws2, Win + (size_t)D*D,  ws1, nullptr, nullptr, D, D, D, D);
  gemm_nt<<<gp,256,0,stream>>>(ws3, Win + (size_t)2*D*D,ws2, nullptr, nullptr, D, D, D, D);

  // 5) scores (scaled, causal, lower-tri tiles)
  scores_kernel<<<dim3(Tq/64, Tq/64, Bc*NHc), 256, 0, stream>>>(ws0, ws1, attnW);

  // 6) softmax in place (writes the attn_weights output, zeros where s>t)
  softmax_kernel<<<dim3(Tq, Bc*NHc), 256, 0, stream>>>(attnW);

  // 7) O = P @ V -> attn_out (ws3)
  pv_kernel<<<dim3(1, Tq/64, Bc*NHc), 256, 0, stream>>>(attnW, ws2, ws3);

  // 8) out projection + bias + residual
  gemm_nt<<<gp,256,0,stream>>>(ws3, Wout, out, bout, x, D, D, D, D);
}

// Round 2
// 1051.928 us; speedup vs baseline: 1.9488x; 1.9488x over previous
//
#include <hip/hip_runtime.h>
#include <math.h>
#include <stdint.h>

typedef unsigned short u16;
typedef __bf16 bf16x8 __attribute__((ext_vector_type(8)));
typedef float f32x4 __attribute__((ext_vector_type(4)));

constexpr int Tq = 2048;
constexpr int D  = 1024;
constexpr int NHc = 16;
constexpr int Bc = 2;
constexpr int Mrows = Bc * Tq;   // 4096

__device__ __forceinline__ float wsum(float v){
#pragma unroll
  for(int o=32;o;o>>=1) v += __shfl_xor(v,o);
  return v;
}
__device__ __forceinline__ float wmax(float v){
#pragma unroll
  for(int o=32;o;o>>=1) v = fmaxf(v,__shfl_xor(v,o));
  return v;
}
__device__ __forceinline__ u16 f2bf(float f){          // RNE fp32->bf16
  union{ float f; unsigned u; } v; v.f = f;
  unsigned r = v.u + 0x7fffu + ((v.u >> 16) & 1u);
  return (u16)(r >> 16);
}
__device__ __forceinline__ float bf2f(u16 b){
  union{ unsigned u; float f; } v; v.u = ((unsigned)b) << 16;
  return v.f;
}
__device__ __forceinline__ void gl2lds16(const void* g, void* l){
  // async global->LDS, 16B/lane; LDS dst = wave-uniform base + lane*16
  __builtin_amdgcn_global_load_lds(
      (const __attribute__((address_space(1))) unsigned int*)g,
      (__attribute__((address_space(3))) unsigned int*)l, 16, 0, 0);
}

// ---------------- fp32 -> bf16 bulk convert (weights) -----------------------
__global__ __launch_bounds__(256) void cvt_kernel(const float* __restrict__ s,
                                                  u16* __restrict__ d){
  const int i = blockIdx.x*256 + threadIdx.x;
  const float4 v = ((const float4*)s)[i];
  ushort4 o; o.x=f2bf(v.x); o.y=f2bf(v.y); o.z=f2bf(v.z); o.w=f2bf(v.w);
  ((ushort4*)d)[i] = o;
}

// ---------------- LayerNorm: one block per row, bf16 out --------------------
__global__ __launch_bounds__(256) void ln_kernel(const float* __restrict__ x,
    const float* __restrict__ g, const float* __restrict__ b,
    u16* __restrict__ xn){
  const int row = blockIdx.x;
  const int tid = threadIdx.x;
  const float4 v = ((const float4*)(x + (size_t)row*D))[tid];
  float s = v.x+v.y+v.z+v.w;
  float q = v.x*v.x+v.y*v.y+v.z*v.z+v.w*v.w;
  s = wsum(s); q = wsum(q);
  __shared__ float sb[4], qb[4];
  if((tid&63)==0){ sb[tid>>6]=s; qb[tid>>6]=q; }
  __syncthreads();
  const float ts = sb[0]+sb[1]+sb[2]+sb[3];
  const float tq = qb[0]+qb[1]+qb[2]+qb[3];
  const float mu   = ts*(1.0f/D);
  const float var  = tq*(1.0f/D) - mu*mu;
  const float rstd = rsqrtf(var + 1e-5f);
  const float4 gv = ((const float4*)g)[tid];
  const float4 bv = ((const float4*)b)[tid];
  ushort4 o;
  o.x = f2bf((v.x-mu)*rstd*gv.x + bv.x);
  o.y = f2bf((v.y-mu)*rstd*gv.y + bv.y);
  o.z = f2bf((v.z-mu)*rstd*gv.z + bv.z);
  o.w = f2bf((v.w-mu)*rstd*gv.w + bv.w);
  ((ushort4*)(xn + (size_t)row*D))[tid] = o;
}

// ---------------- bf16 MFMA NT GEMM: C = A @ B^T ---------------------------
// A (M,K) row-major bf16, B (N,K) row-major bf16. 128x128 tile, BK=32,
// 256 thr = 4 waves in 2x2, each wave 64x64 = 4x4 MFMA 16x16x32 tiles.
// MODE 0: out bf16 (+optional fp32 bias)
// MODE 1: out fp32 + bias + residual
// MODE 2: scores — z-batched per-head slices, skip upper-tri tiles,
//         out fp32 scaled by 0.125
template<int MODE>
__global__ __launch_bounds__(256) void gemm_bf16(
    const u16* __restrict__ A, const u16* __restrict__ B, void* __restrict__ Cv,
    const float* __restrict__ bias, const float* __restrict__ resid,
    int K, int lda, int ldb, int ldc){
  if(MODE==2 && blockIdx.x > blockIdx.y) return;   // fully-masked tile
  size_t aOff = 0, bOff = 0, cOff = 0;
  if(MODE==2){
    const int z = blockIdx.z;
    aOff = (size_t)(z>>4)*Tq*D + (size_t)(z&15)*64;
    bOff = aOff;
    cOff = (size_t)z*Tq*Tq;
  }
  __shared__ __align__(16) u16 As[128*32];
  __shared__ __align__(16) u16 Bs[128*32];
  const int tid  = threadIdx.x;
  const int lane = tid & 63, wv = tid >> 6;
  const int wRow = (wv >> 1) * 64, wCol = (wv & 1) * 64;
  const int mBase = blockIdx.y*128, nBase = blockIdx.x*128;
  const int quad = lane >> 4, r16 = lane & 15;
  const int sRow = lane >> 2;            // staging row within 16-row chunk
  const int sCol = (lane & 3) * 8;       // staging k-offset (elements)
  const char* smemA = (const char*)As;
  const char* smemB = (const char*)Bs;

  f32x4 acc[4][4];
#pragma unroll
  for(int i=0;i<4;i++)
#pragma unroll
    for(int j=0;j<4;j++) acc[i][j] = (f32x4)(0.f);

  for(int k0=0;k0<K;k0+=32){
#pragma unroll
    for(int rdn=0;rdn<2;rdn++){
      const int row = rdn*64 + wv*16 + sRow;
      gl2lds16(A + aOff + (size_t)(mBase + row)*lda + k0 + sCol,
               (void*)((char*)As + rdn*4096 + wv*1024));
      gl2lds16(B + bOff + (size_t)(nBase + row)*ldb + k0 + sCol,
               (void*)((char*)Bs + rdn*4096 + wv*1024));
    }
    __syncthreads();
    bf16x8 af[4], bfr[4];
#pragma unroll
    for(int i=0;i<4;i++)
      af[i]  = *(const bf16x8*)(smemA + (wRow + i*16 + r16)*64 + quad*16);
#pragma unroll
    for(int j=0;j<4;j++)
      bfr[j] = *(const bf16x8*)(smemB + (wCol + j*16 + r16)*64 + quad*16);
#pragma unroll
    for(int i=0;i<4;i++)
#pragma unroll
      for(int j=0;j<4;j++)
        acc[i][j] = __builtin_amdgcn_mfma_f32_16x16x32_bf16(af[i], bfr[j], acc[i][j], 0,0,0);
    __syncthreads();
  }

  // epilogue: C/D layout col=lane&15, row=quad*4+reg
#pragma unroll
  for(int i=0;i<4;i++){
#pragma unroll
    for(int j=0;j<4;j++){
      const int n = nBase + wCol + j*16 + r16;
      if(MODE==0){
        u16* C = (u16*)Cv;
        const float bv = bias ? bias[n] : 0.f;
#pragma unroll
        for(int reg=0;reg<4;reg++){
          const int m = mBase + wRow + i*16 + quad*4 + reg;
          C[(size_t)m*ldc + n] = f2bf(acc[i][j][reg] + bv);
        }
      } else if(MODE==1){
        float* C = (float*)Cv;
        const float bv = bias[n];
#pragma unroll
        for(int reg=0;reg<4;reg++){
          const int m = mBase + wRow + i*16 + quad*4 + reg;
          C[(size_t)m*ldc + n] = acc[i][j][reg] + bv + resid[(size_t)m*ldc + n];
        }
      } else {
        float* C = (float*)Cv + cOff;
#pragma unroll
        for(int reg=0;reg<4;reg++){
          const int m = mBase + wRow + i*16 + quad*4 + reg;
          C[(size_t)m*ldc + n] = acc[i][j][reg] * 0.125f;
        }
      }
    }
  }
}

// ---------------- RoPE (split-half), in place on bf16 q1,k1 -----------------
__global__ __launch_bounds__(256) void rope_kernel(u16* __restrict__ q,
                                                   u16* __restrict__ k){
  const int idx = blockIdx.x*256 + threadIdx.x;
  const int m = idx >> 9;
  const int r = idx & 511;
  const int h = r >> 5, i = r & 31;
  const int t = m & (Tq-1);
  const float inv_freq = powf(10000.0f, -(float)i*(1.0f/32.0f));
  const float ang = (float)t * inv_freq;
  const float c = cosf(ang), s = sinf(ang);
  const size_t base = (size_t)m*D + h*64 + i;
  const float a0=bf2f(q[base]), a1=bf2f(q[base+32]);
  q[base]    = f2bf(a0*c - a1*s);
  q[base+32] = f2bf(a1*c + a0*s);
  const float b0=bf2f(k[base]), b1=bf2f(k[base+32]);
  k[base]    = f2bf(b0*c - b1*s);
  k[base+32] = f2bf(b1*c + b0*s);
}

// ---------------- transpose V: (B,T,D) bf16 -> (BH,64,T) bf16 ---------------
__global__ __launch_bounds__(256) void transpose_v(const u16* __restrict__ v2,
                                                   u16* __restrict__ Vt){
  __shared__ u16 tile[64][65];
  const int bt = blockIdx.x;        // t tile
  const int bh = blockIdx.y;
  const int b = bh >> 4, h = bh & 15;
  const int tid = threadIdx.x;
  const int t0 = bt*64;
#pragma unroll
  for(int rep=0;rep<4;rep++){
    const int tl = rep*16 + (tid>>4);
    const int dl = (tid&15)*4;
    const ushort4 val = *(const ushort4*)(v2 + (size_t)((size_t)b*Tq + t0 + tl)*D + h*64 + dl);
    tile[tl][dl+0]=val.x; tile[tl][dl+1]=val.y; tile[tl][dl+2]=val.z; tile[tl][dl+3]=val.w;
  }
  __syncthreads();
#pragma unroll
  for(int rep=0;rep<4;rep++){
    const int dl = rep*16 + (tid>>4);
    const int tl = (tid&15)*4;
    ushort4 o;
    o.x=tile[tl+0][dl]; o.y=tile[tl+1][dl]; o.z=tile[tl+2][dl]; o.w=tile[tl+3][dl];
    *(ushort4*)(Vt + ((size_t)bh*64 + dl)*Tq + t0 + tl) = o;
  }
}

// ---------------- row softmax in place (reads causal half only) -------------
__global__ __launch_bounds__(256) void softmax_kernel(float* __restrict__ attnW){
  const int t  = blockIdx.x;
  const int bh = blockIdx.y;
  float* row = attnW + (size_t)bh*Tq*Tq + (size_t)t*Tq;
  const int tid = threadIdx.x;
  const int s0 = tid*8;
  float vals[8];
  if(s0 <= t){
    const float4 v0 = ((const float4*)row)[tid*2];
    const float4 v1 = ((const float4*)row)[tid*2+1];
    vals[0]=v0.x; vals[1]=v0.y; vals[2]=v0.z; vals[3]=v0.w;
    vals[4]=v1.x; vals[5]=v1.y; vals[6]=v1.z; vals[7]=v1.w;
#pragma unroll
    for(int p=0;p<8;p++) if(s0+p > t) vals[p] = -1e30f;
  } else {
#pragma unroll
    for(int p=0;p<8;p++) vals[p] = -1e30f;
  }
  float mx = -1e30f;
#pragma unroll
  for(int p=0;p<8;p++) mx = fmaxf(mx, vals[p]);
  mx = wmax(mx);
  __shared__ float sm[4], ss[4];
  if((tid&63)==0) sm[tid>>6]=mx;
  __syncthreads();
  mx = fmaxf(fmaxf(sm[0],sm[1]), fmaxf(sm[2],sm[3]));
  float lsum = 0.f;
#pragma unroll
  for(int p=0;p<8;p++){ vals[p] = __expf(vals[p]-mx); lsum += vals[p]; }
  lsum = wsum(lsum);
  if((tid&63)==0) ss[tid>>6]=lsum;
  __syncthreads();
  const float inv = 1.0f/(ss[0]+ss[1]+ss[2]+ss[3]);
  ((float4*)row)[tid*2]   = make_float4(vals[0]*inv, vals[1]*inv, vals[2]*inv, vals[3]*inv);
  ((float4*)row)[tid*2+1] = make_float4(vals[4]*inv, vals[5]*inv, vals[6]*inv, vals[7]*inv);
}

// ---------------- PV: O = P @ V (P fp32->bf16 on the fly, MFMA) -------------
// grid (tRow=T/128, bh). Tile 128x64, BK=32, causal k-bound.
__global__ __launch_bounds__(256) void pv_kernel(const float* __restrict__ attnW,
    const u16* __restrict__ Vt, u16* __restrict__ O){
  __shared__ __align__(16) u16 Ps[128*32];
  __shared__ __align__(16) u16 Vs[64*32];
  const int tRow = blockIdx.x;
  const int bh = blockIdx.y; const int b = bh >> 4, h = bh & 15;
  const float* Pg  = attnW + (size_t)bh*Tq*Tq;
  const u16*   Vtb = Vt + (size_t)bh*64*Tq;
  const int tid  = threadIdx.x;
  const int lane = tid & 63, wv = tid >> 6;
  const int wRow = (wv >> 1) * 64, wCol = (wv & 1) * 32;
  const int mBase = tRow*128;
  const int quad = lane >> 4, r16 = lane & 15;
  const char* smemP = (const char*)Ps;
  const char* smemV = (const char*)Vs;

  f32x4 acc[4][2];
#pragma unroll
  for(int i=0;i<4;i++){ acc[i][0]=(f32x4)(0.f); acc[i][1]=(f32x4)(0.f); }

  const int kEnd = (tRow+1)*128;
  for(int k0=0;k0<kEnd;k0+=32){
    // stage P tile 128x32 (fp32 -> bf16)
#pragma unroll
    for(int r=0;r<4;r++){
      const int row = r*32 + (tid>>3);
      const int cOffE = (tid&7)*4;
      const float4 v = *(const float4*)(Pg + (size_t)(mBase+row)*Tq + k0 + cOffE);
      ushort4 o; o.x=f2bf(v.x); o.y=f2bf(v.y); o.z=f2bf(v.z); o.w=f2bf(v.w);
      *(ushort4*)(Ps + row*32 + cOffE) = o;
    }
    // stage V tile 64x32 (bf16 async)
    gl2lds16(Vtb + (size_t)(wv*16 + (lane>>2))*Tq + k0 + (lane&3)*8,
             (void*)((char*)Vs + wv*1024));
    __syncthreads();
    bf16x8 af[4], bfr[2];
#pragma unroll
    for(int i=0;i<4;i++)
      af[i]  = *(const bf16x8*)(smemP + (wRow + i*16 + r16)*64 + quad*16);
#pragma unroll
    for(int j=0;j<2;j++)
      bfr[j] = *(const bf16x8*)(smemV + (wCol + j*16 + r16)*64 + quad*16);
#pragma unroll
    for(int i=0;i<4;i++)
#pragma unroll
      for(int j=0;j<2;j++)
        acc[i][j] = __builtin_amdgcn_mfma_f32_16x16x32_bf16(af[i], bfr[j], acc[i][j], 0,0,0);
    __syncthreads();
  }
#pragma unroll
  for(int i=0;i<4;i++){
#pragma unroll
    for(int j=0;j<2;j++){
      const int n = wCol + j*16 + r16;      // d within head
#pragma unroll
      for(int reg=0;reg<4;reg++){
        const int m = mBase + wRow + i*16 + quad*4 + reg;   // t
        O[((size_t)b*Tq + m)*D + h*64 + n] = f2bf(acc[i][j][reg]);
      }
    }
  }
}

extern "C" void kernel_launch(void* const* d_in, const int* in_sizes, int n_in,
                              void* d_out, int out_size, void* d_ws, size_t ws_size,
                              hipStream_t stream){
  const float* x    = (const float*)d_in[0];
  const float* Win  = (const float*)d_in[1];   // (3072,1024)
  const float* bin  = (const float*)d_in[2];   // (3072)
  const float* Wout = (const float*)d_in[3];   // (1024,1024)
  const float* bout = (const float*)d_in[4];   // (1024)
  const float* gam  = (const float*)d_in[5];
  const float* bet  = (const float*)d_in[6];

  float* out   = (float*)d_out;
  float* attnW = out + (size_t)Mrows*D;        // (B,H,T,T) fp32

  // ws layout (bytes), 64 MB total:
  const size_t MB = 1u<<20;
  char* ws = (char*)d_ws;
  u16* Winb  = (u16*)(ws + 0);        // 6 MB (3M bf16)
  u16* Woutb = (u16*)(ws + 6*MB);     // 2 MB
  u16* xn    = (u16*)(ws + 8*MB);     // 8 MB  -> reused as Vt
  u16* Vt    = xn;
  u16* q1    = (u16*)(ws + 16*MB);    // 8 MB  -> reused as O
  u16* Oat   = q1;
  u16* k1    = (u16*)(ws + 24*MB);
  u16* v1    = (u16*)(ws + 32*MB);
  u16* q2    = (u16*)(ws + 40*MB);
  u16* k2    = (u16*)(ws + 48*MB);
  u16* v2    = (u16*)(ws + 56*MB);

  const size_t DD = (size_t)D*D;

  // 0) weight conversion fp32 -> bf16
  cvt_kernel<<<(3*DD/4)/256, 256, 0, stream>>>(Win, Winb);
  cvt_kernel<<<(DD/4)/256, 256, 0, stream>>>(Wout, Woutb);

  // 1) LayerNorm -> bf16
  ln_kernel<<<Mrows, 256, 0, stream>>>(x, gam, bet, xn);

  // 2) first projection (+bias): q1,k1,v1 bf16
  const dim3 gp(D/128, Mrows/128, 1);   // (8,32)
  gemm_bf16<0><<<gp,256,0,stream>>>(xn, Winb,        q1, bin,      nullptr, D, D, D, D);
  gemm_bf16<0><<<gp,256,0,stream>>>(xn, Winb+DD,     k1, bin+D,    nullptr, D, D, D, D);
  gemm_bf16<0><<<gp,256,0,stream>>>(xn, Winb+2*DD,   v1, bin+2*D,  nullptr, D, D, D, D);

  // 3) RoPE in place on q1,k1
  rope_kernel<<<(Mrows*512)/256, 256, 0, stream>>>(q1, k1);

  // 4) second projection (no bias): q2,k2,v2 bf16
  gemm_bf16<0><<<gp,256,0,stream>>>(q1, Winb,        q2, nullptr, nullptr, D, D, D, D);
  gemm_bf16<0><<<gp,256,0,stream>>>(k1, Winb+DD,     k2, nullptr, nullptr, D, D, D, D);
  gemm_bf16<0><<<gp,256,0,stream>>>(v1, Winb+2*DD,   v2, nullptr, nullptr, D, D, D, D);

  // 5) transpose V -> (BH,64,T)
  transpose_v<<<dim3(Tq/64, Bc*NHc), 256, 0, stream>>>(v2, Vt);

  // 6) scores = 0.125 * q2 @ k2^T per head (lower-tri tiles), fp32 -> attnW
  gemm_bf16<2><<<dim3(Tq/128, Tq/128, Bc*NHc),256,0,stream>>>(
      q2, k2, attnW, nullptr, nullptr, 64, D, D, Tq);

  // 7) softmax in place (writes full rows incl. zeros above diagonal)
  softmax_kernel<<<dim3(Tq, Bc*NHc), 256, 0, stream>>>(attnW);

  // 8) O = P @ V  (bf16 out)
  pv_kernel<<<dim3(Tq/128, Bc*NHc), 256, 0, stream>>>(attnW, Vt, Oat);

  // 9) out projection + bias + residual (fp32 out)
  gemm_bf16<1><<<gp,256,0,stream>>>(Oat, Woutb, out, bout, x, D, D, D, D);
}